// Round 11
// baseline (2977.767 us; speedup 1.0000x reference)
//
#include <hip/hip_runtime.h>

// ---------- constants ----------
#define B_    16
#define NCTX  8
#define BIN_  256
#define LQ_   256
#define L_    520          // NCTX + BIN + LQ
#define LSEQ  1024
#define D_    1024
#define H_    16
#define DH    64
#define DFF_  4096
#define DEPTH 6
#define MROWS (B_ * L_)    // 8320 = 65 * 128
#define GY    65           // M tiles of 128

using bf16x8 = __attribute__((ext_vector_type(8))) __bf16;
using bf16x4 = __attribute__((ext_vector_type(4))) __bf16;
using f32x4  = __attribute__((ext_vector_type(4))) float;

#define DEV __device__ __forceinline__

// element offset into a [rows][64] bf16 tile, XOR-swizzled 16B chunks
DEV int swz(int r, int c) { return (r << 6) + (((c ^ r) & 7) << 3); }

#define GLDS16(g, l)                                                         \
  __builtin_amdgcn_global_load_lds(                                          \
      (__attribute__((address_space(1))) void*)(g),                          \
      (__attribute__((address_space(3))) void*)(l), 16, 0, 0)

// ---------- prologue kernels ----------

// Te[b][pos]: time key per decoder position, per-64-tile K-min / Q-max for
// attention tile skipping, plus time-bin histogram counts for pooling.
__global__ void te_k(const int* __restrict__ qtime, const int* __restrict__ tIdx,
                     int* __restrict__ Te, int* __restrict__ TeMinK,
                     int* __restrict__ TeMaxQ, int* __restrict__ cnts) {
  int b = blockIdx.x, pos = threadIdx.x;  // 576 threads
  __shared__ int smin[9], smax[9], hc[256];
  if (pos < 9) { smin[pos] = 0x7fffffff; smax[pos] = (int)0x80000000; }
  if (pos < 256) hc[pos] = 0;
  __syncthreads();
  int v;
  if (pos < NCTX) v = (int)0x80000000;
  else if (pos < NCTX + BIN_) v = pos - NCTX;
  else if (pos < L_) v = qtime[b * LQ_ + (pos - NCTX - BIN_)];
  else v = 0x7fffffff;
  Te[b * 576 + pos] = v;
  int vq = (pos < L_) ? v : (int)0x80000000;
  atomicMin(&smin[pos >> 6], v);
  atomicMax(&smax[pos >> 6], vq);
  for (int i = pos; i < LSEQ; i += 576) atomicAdd(&hc[tIdx[b * LSEQ + i]], 1);
  __syncthreads();
  if (pos < 9) { TeMinK[b * 9 + pos] = smin[pos]; TeMaxQ[b * 9 + pos] = smax[pos]; }
  if (pos < 256) cnts[b * 256 + pos] = hc[pos];
}

// histogram-style mean-pool: block (colgroup cg of 32 cols, b). Each latent
// element is read exactly once; LDS fp32 atomic accumulate per (bin, col).
__global__ __launch_bounds__(256) void pool_k(const float* __restrict__ latents,
                                              const int* __restrict__ tIdx,
                                              const int* __restrict__ cnts,
                                              const float* __restrict__ temb,
                                              float* __restrict__ h) {
  const int cg = blockIdx.x, b = blockIdx.y, tid = threadIdx.x;
  __shared__ float acc[256][33];
  __shared__ int sIdx[LSEQ];
  float* af = &acc[0][0];
  for (int i = tid; i < 256 * 33; i += 256) af[i] = 0.f;
#pragma unroll
  for (int j = 0; j < 4; ++j) sIdx[tid + 256 * j] = tIdx[b * LSEQ + tid + 256 * j];
  __syncthreads();
  const int col = tid & 31, rp = tid >> 5;
  const float* Lb = latents + (size_t)b * LSEQ * D_ + cg * 32 + col;
  for (int r = rp; r < LSEQ; r += 8)
    atomicAdd(&acc[sIdx[r]][col], Lb[(size_t)r * D_]);
  __syncthreads();
  for (int s = rp; s < 256; s += 8) {
    int c = cnts[b * 256 + s];
    float inv = 1.f / (float)(c > 0 ? c : 1);
    h[((size_t)b * L_ + NCTX + s) * D_ + cg * 32 + col] =
        acc[s][col] * inv + temb[(size_t)s * D_ + cg * 32 + col];
  }
}

// ctx rows (0..7) + query rows (264..519)
__global__ void qrows_k(const float* __restrict__ ctx,
                        const float* __restrict__ qemb,
                        const float* __restrict__ temb,
                        const int* __restrict__ qidx,
                        const int* __restrict__ qtime, float* __restrict__ h) {
  int r = blockIdx.x, b = blockIdx.y, tid = threadIdx.x;
  if (r < NCTX) {
    float4 v = ((const float4*)(ctx + ((size_t)b * NCTX + r) * D_))[tid];
    ((float4*)(h + ((size_t)b * L_ + r) * D_))[tid] = v;
  } else {
    int q = r - NCTX;
    int qi = qidx[b * LQ_ + q];
    int qt = qtime[b * LQ_ + q];
    float4 e = ((const float4*)(qemb + (size_t)qi * D_))[tid];
    float4 t = ((const float4*)(temb + (size_t)qt * D_))[tid];
    float4 o; o.x = e.x + t.x; o.y = e.y + t.y; o.z = e.z + t.z; o.w = e.w + t.w;
    ((float4*)(h + ((size_t)b * L_ + NCTX + BIN_ + q) * D_))[tid] = o;
  }
}

// one launch per layer: convert all 4 weight slabs fp32 -> bf16
__global__ void cvt4_k(const float* __restrict__ s0, const float* __restrict__ s1,
                       const float* __restrict__ s2, const float* __restrict__ s3,
                       __bf16* __restrict__ dst) {
  int i = blockIdx.x * 256 + threadIdx.x;  // 3145728 total float4s
  const float* s; int off;
  if (i < 786432)       { s = s0; off = i; }
  else if (i < 1048576) { s = s1; off = i - 786432; }
  else if (i < 2097152) { s = s2; off = i - 1048576; }
  else                  { s = s3; off = i - 2097152; }
  float4 v = ((const float4*)s)[off];
  bf16x4 o;
  o[0] = (__bf16)v.x; o[1] = (__bf16)v.y; o[2] = (__bf16)v.z; o[3] = (__bf16)v.w;
  ((bf16x4*)dst)[i] = o;
}

// LayerNorm over D=1024: wave-per-row, no LDS, no __syncthreads.
__global__ __launch_bounds__(256) void ln_k(const float* __restrict__ h,
                                            const float* __restrict__ s,
                                            const float* __restrict__ bb,
                                            __bf16* __restrict__ y) {
  const int lane = threadIdx.x & 63, wave = threadIdx.x >> 6;
  const int row = blockIdx.x * 4 + wave;
  const float4* hr = (const float4*)(h + (size_t)row * D_);
  float4 v[4];
  float sum = 0.f, sq = 0.f;
#pragma unroll
  for (int j = 0; j < 4; ++j) {
    v[j] = hr[lane + 64 * j];
    sum += v[j].x + v[j].y + v[j].z + v[j].w;
    sq += v[j].x * v[j].x + v[j].y * v[j].y + v[j].z * v[j].z + v[j].w * v[j].w;
  }
#pragma unroll
  for (int m = 32; m; m >>= 1) { sum += __shfl_xor(sum, m); sq += __shfl_xor(sq, m); }
  float mean = sum * (1.f / D_);
  float var  = sq * (1.f / D_) - mean * mean;
  float rstd = rsqrtf(var + 1e-5f);
#pragma unroll
  for (int j = 0; j < 4; ++j) {
    float4 sv = ((const float4*)s)[lane + 64 * j];
    float4 bv = ((const float4*)bb)[lane + 64 * j];
    bf16x4 o;
    o[0] = (__bf16)((v[j].x - mean) * rstd * sv.x + bv.x);
    o[1] = (__bf16)((v[j].y - mean) * rstd * sv.y + bv.y);
    o[2] = (__bf16)((v[j].z - mean) * rstd * sv.z + bv.z);
    o[3] = (__bf16)((v[j].w - mean) * rstd * sv.w + bv.w);
    *(bf16x4*)(y + (size_t)row * D_ + (lane + 64 * j) * 4) = o;
  }
}

// ---------- GEMM: C[M,N] = A[M,K] * Bw[N,K]^T + bias (128x128 tile) ----------
// Proven core (r3 fingerprint: 126us, VGPR 84, 32KB LDS): single-buffer,
// 2 barriers/K-step; XCD-bijective chunk + 8-row supertile bands.
// EPI 0: store bf16; 1: outF += val (fp32 residual); 2: gelu -> bf16;
// EPI 4 (qkv): QK columns -> outB; V columns (bn>=2048) -> outV transposed
//              per (b,h): outV[b*1024 + (cg-2048)][row-in-batch], ld 576.
template <int EPI>
__global__ __launch_bounds__(256) void gemm_k(const __bf16* __restrict__ A,
                                              const __bf16* __restrict__ Bw,
                                              const float* __restrict__ bias,
                                              __bf16* __restrict__ outB,
                                              float* __restrict__ outF,
                                              __bf16* __restrict__ outV,
                                              int N, int K, int gx) {
  __shared__ __bf16 sA[128 * 64];
  __shared__ __bf16 sB[128 * 64];
  const int tid = threadIdx.x;
  const int lane = tid & 63, wave = tid >> 6;
  const int lr = lane & 15, lq = lane >> 4;
  const int wr = wave >> 1, wc = wave & 1;

  // XCD-bijective remap (gridDim.x % 8 == 0 always) then 8-row bands
  const int nwg = gridDim.x;
  int hid = blockIdx.x;
  int lid = (hid & 7) * (nwg >> 3) + (hid >> 3);
  int per_band = gx << 3;
  int band = lid / per_band;
  int rem = lid - band * per_band;
  int rows = min(8, GY - (band << 3));
  int by = (band << 3) + rem % rows;
  int bx = rem / rows;
  const size_t bm = (size_t)by * 128;
  const size_t bn = (size_t)bx * 128;

  f32x4 acc[4][4] = {};

  int stage_r[4], stage_src[4];
#pragma unroll
  for (int j = 0; j < 4; ++j) {
    int q = (wave * 4 + j) * 64 + lane;
    int r = q >> 3, c = q & 7;
    stage_r[j] = r;
    stage_src[j] = ((c ^ r) & 7) << 3;  // pre-swizzled global chunk
  }
  const __bf16* Ab = A + bm * (size_t)K;
  const __bf16* Bb = Bw + bn * (size_t)K;
  const int nk = K >> 6;
  for (int kt = 0; kt < nk; ++kt) {
    const __bf16* Ak = Ab + kt * 64;
    const __bf16* Bk = Bb + kt * 64;
#pragma unroll
    for (int j = 0; j < 4; ++j) {
      int r = stage_r[j];
      GLDS16(Ak + (size_t)r * K + stage_src[j], sA + (wave * 4 + j) * 512);
      GLDS16(Bk + (size_t)r * K + stage_src[j], sB + (wave * 4 + j) * 512);
    }
    __syncthreads();
#pragma unroll
    for (int kk = 0; kk < 2; ++kk) {
      bf16x8 af[4], bfm[4];
#pragma unroll
      for (int im = 0; im < 4; ++im)
        af[im] = *(const bf16x8*)(sA + swz(wr * 64 + im * 16 + lr, kk * 4 + lq));
#pragma unroll
      for (int in = 0; in < 4; ++in)
        bfm[in] = *(const bf16x8*)(sB + swz(wc * 64 + in * 16 + lr, kk * 4 + lq));
#pragma unroll
      for (int im = 0; im < 4; ++im)
#pragma unroll
        for (int in = 0; in < 4; ++in)
          acc[im][in] = __builtin_amdgcn_mfma_f32_16x16x32_bf16(af[im], bfm[in], acc[im][in], 0, 0, 0);
    }
    __syncthreads();
  }
  const int r0 = (int)bm + wr * 64 + lq * 4;
  const int c0 = (int)bn + wc * 64 + lr;
#pragma unroll
  for (int in = 0; in < 4; ++in) {
    int cg = c0 + in * 16;
    float bl = bias[cg];
#pragma unroll
    for (int im = 0; im < 4; ++im) {
      f32x4 v = acc[im][in];
#pragma unroll
      for (int i = 0; i < 4; ++i) {
        int rg = r0 + im * 16 + i;
        float val = v[i] + bl;
        if (EPI == 0) {
          outB[(size_t)rg * N + cg] = (__bf16)val;
        } else if (EPI == 1) {
          outF[(size_t)rg * N + cg] += val;
        } else if (EPI == 2) {
          float g = 0.5f * val * (1.0f + erff(val * 0.70710678118f));
          outB[(size_t)rg * N + cg] = (__bf16)g;
        } else {  // EPI == 4
          if (bn < 2048) {
            outB[(size_t)rg * N + cg] = (__bf16)val;
          } else {
            int b2 = (int)(((float)rg + 0.5f) * (1.0f / 520.0f));
            int rr = rg - b2 * 520;
            outV[((size_t)b2 * 1024 + (size_t)(cg - 2048)) * 576 + rr] = (__bf16)val;
          }
        }
      }
    }
  }
}

// ---------- attention ----------
// grid (qt=9, h=16, b=16), 256 threads (4 waves); each wave owns 16 q rows.
// Q in registers; K staged swizzled; V read from pre-transposed vtb and
// staged swizzled, so PV B-fragments are single b128 reads (same pattern as
// QK's K reads -- hardware-verified conflict-free). Fully-masked (qt,kt)
// tile pairs skipped (time keys sorted).
__global__ __launch_bounds__(256) void attn_k(const __bf16* __restrict__ qkv,
                                              const __bf16* __restrict__ vtb,
                                              const int* __restrict__ Te,
                                              const int* __restrict__ TeMinK,
                                              const int* __restrict__ TeMaxQ,
                                              __bf16* __restrict__ o) {
  const int qt = blockIdx.x, hh = blockIdx.y, b = blockIdx.z;
  const int tid = threadIdx.x;
  const int lane = tid & 63, wave = tid >> 6;
  const int lr = lane & 15, lq = lane >> 4;
  __shared__ __bf16 sK[64 * 64], sVT[64 * 64];
  __shared__ __bf16 sP[4][16 * 64];
  __shared__ int sTq[64], sTk[64];

  if (tid < 64) sTq[tid] = Te[b * 576 + qt * 64 + tid];
  const int maxQ = TeMaxQ[b * 9 + qt];

  const __bf16* base = qkv + (size_t)b * L_ * (3 * D_) + hh * DH;
  const __bf16* vbase = vtb + ((size_t)b * 1024 + hh * 64) * 576;

  // Q fragments in registers: this wave's 16 rows, lane (lr,lq) holds
  // Q[qt*64+wave*16+lr][kk*32 + lq*8 .. +8) for kk=0,1.
  bf16x8 qf0 = {}, qf1 = {};
  {
    int qrow = qt * 64 + wave * 16 + lr;
    if (qrow < L_) {
      const __bf16* qp = base + (size_t)qrow * (3 * D_);
      qf0 = *(const bf16x8*)(qp + lq * 8);
      qf1 = *(const bf16x8*)(qp + 32 + lq * 8);
    }
  }

  float m_run[4], l_run[4];
#pragma unroll
  for (int i = 0; i < 4; ++i) { m_run[i] = -1e30f; l_run[i] = 0.f; }
  f32x4 oacc[4] = {};
  const float scale = 0.125f;

  for (int kt = 0; kt < 9; ++kt) {
    if (TeMinK[b * 9 + kt] > maxQ) continue;  // tile fully masked (uniform)
    __syncthreads();  // previous tile fully consumed
    if (tid < 64) sTk[tid] = Te[b * 576 + kt * 64 + tid];
#pragma unroll
    for (int j = 0; j < 2; ++j) {
      int q = tid + j * 256;
      int r = q >> 3, c = q & 7;
      // K: rows are kv positions
      int rg = kt * 64 + r;
      bf16x8 kv = {};
      if (rg < L_) kv = *(const bf16x8*)(base + D_ + (size_t)rg * (3 * D_) + c * 8);
      *(bf16x8*)(sK + swz(r, c)) = kv;
      // V^T: rows are d (always valid), cols are kv (chunk-aligned guard)
      int kv0 = kt * 64 + c * 8;
      bf16x8 vv = {};
      if (kv0 < L_) vv = *(const bf16x8*)(vbase + (size_t)r * 576 + kv0);
      *(bf16x8*)(sVT + swz(r, c)) = vv;
    }
    __syncthreads();

    // S = Q K^T (wave strip: rows wave*16..+16, cols 0..64)
    f32x4 sacc[4] = {};
    __builtin_amdgcn_s_setprio(1);
#pragma unroll
    for (int kk = 0; kk < 2; ++kk) {
      bf16x8 aq = (kk == 0) ? qf0 : qf1;
#pragma unroll
      for (int cn = 0; cn < 4; ++cn) {
        bf16x8 bk = *(const bf16x8*)(sK + swz(cn * 16 + lr, kk * 4 + lq));
        sacc[cn] = __builtin_amdgcn_mfma_f32_16x16x32_bf16(aq, bk, sacc[cn], 0, 0, 0);
      }
    }
    __builtin_amdgcn_s_setprio(0);
    // mask + online softmax (rows: lq*4+i, cols: cn*16+lr)
    float sval[4][4], mt[4];
#pragma unroll
    for (int i = 0; i < 4; ++i) mt[i] = -1e30f;
#pragma unroll
    for (int cn = 0; cn < 4; ++cn) {
      int tk = sTk[cn * 16 + lr];
#pragma unroll
      for (int i = 0; i < 4; ++i) {
        int tq = sTq[wave * 16 + lq * 4 + i];
        float sv = sacc[cn][i] * scale + ((tq < tk) ? -1e9f : 0.f);
        sval[cn][i] = sv;
        mt[i] = fmaxf(mt[i], sv);
      }
    }
#pragma unroll
    for (int i = 0; i < 4; ++i) {
#pragma unroll
      for (int m = 1; m < 16; m <<= 1) mt[i] = fmaxf(mt[i], __shfl_xor(mt[i], m));
    }
    float fsc[4], lt[4];
    __bf16* sPw = sP[wave];
#pragma unroll
    for (int i = 0; i < 4; ++i) {
      float mnew = fmaxf(m_run[i], mt[i]);
      fsc[i] = __expf(m_run[i] - mnew);
      m_run[i] = mnew;
      lt[i] = 0.f;
    }
#pragma unroll
    for (int cn = 0; cn < 4; ++cn) {
#pragma unroll
      for (int i = 0; i < 4; ++i) {
        float p = __expf(sval[cn][i] - m_run[i]);
        lt[i] += p;
        int rp = lq * 4 + i;
        int kvx = cn * 16 + lr;
        sPw[(rp << 6) + ((((kvx >> 3) ^ rp) & 7) << 3) + (kvx & 7)] = (__bf16)p;
      }
    }
#pragma unroll
    for (int i = 0; i < 4; ++i) {
#pragma unroll
      for (int m = 1; m < 16; m <<= 1) lt[i] += __shfl_xor(lt[i], m);
      l_run[i] = l_run[i] * fsc[i] + lt[i];
    }
#pragma unroll
    for (int dn = 0; dn < 4; ++dn)
#pragma unroll
      for (int i = 0; i < 4; ++i) oacc[dn][i] *= fsc[i];

    // PV: O += P[16,64] * V[64,64]; B-fragment = V^T row slice (b128, swz)
    __builtin_amdgcn_s_setprio(1);
#pragma unroll
    for (int kk = 0; kk < 2; ++kk) {
      bf16x8 ap = *(const bf16x8*)(sPw + swz(lr, kk * 4 + lq));
#pragma unroll
      for (int dn = 0; dn < 4; ++dn) {
        bf16x8 bv = *(const bf16x8*)(sVT + swz(dn * 16 + lr, kk * 4 + lq));
        oacc[dn] = __builtin_amdgcn_mfma_f32_16x16x32_bf16(ap, bv, oacc[dn], 0, 0, 0);
      }
    }
    __builtin_amdgcn_s_setprio(0);
  }
  // write O (normalize)
#pragma unroll
  for (int dn = 0; dn < 4; ++dn) {
#pragma unroll
    for (int i = 0; i < 4; ++i) {
      int rg = qt * 64 + wave * 16 + lq * 4 + i;
      if (rg < L_) {
        float val = oacc[dn][i] / l_run[i];
        o[((size_t)b * L_ + rg) * D_ + hh * DH + dn * 16 + lr] = (__bf16)val;
      }
    }
  }
}

// copy h[:, 8:, :] -> out (fp32)
__global__ void out_k(const float* __restrict__ h, float* __restrict__ out) {
  int idx = blockIdx.x * 256 + threadIdx.x;  // float4 units, 16*512*256
  int c4 = idx & 255;
  int r = (idx >> 8) & 511;
  int b = idx >> 17;
  ((float4*)out)[idx] = ((const float4*)h)[((size_t)b * L_ + NCTX + r) * 256 + c4];
}

// ---------- host ----------
extern "C" void kernel_launch(void* const* d_in, const int* in_sizes, int n_in,
                              void* d_out, int out_size, void* d_ws, size_t ws_size,
                              hipStream_t stream) {
  const float* latents      = (const float*)d_in[0];
  const int*   in_time_idx  = (const int*)d_in[1];
  const int*   query_idx    = (const int*)d_in[4];
  const int*   query_time   = (const int*)d_in[5];
  const float* ctx_emb      = (const float*)d_in[8];
  const float* query_emb_w  = (const float*)d_in[9];
  const float* time_emb_w   = (const float*)d_in[10];
  const float* qkv_w        = (const float*)d_in[11];
  const float* qkv_b        = (const float*)d_in[12];
  const float* out_w        = (const float*)d_in[13];
  const float* out_b        = (const float*)d_in[14];
  const float* ln1_s        = (const float*)d_in[15];
  const float* ln1_b        = (const float*)d_in[16];
  const float* ln2_s        = (const float*)d_in[17];
  const float* ln2_b        = (const float*)d_in[18];
  const float* w1           = (const float*)d_in[19];
  const float* b1           = (const float*)d_in[20];
  const float* w2           = (const float*)d_in[21];
  const float* b2           = (const float*)d_in[22];

  size_t off = 0;
  auto alloc = [&](size_t n) { char* p = (char*)d_ws + off; off += (n + 255) & ~(size_t)255; return (void*)p; };
  float*  h    = (float*)alloc((size_t)MROWS * D_ * 4);
  __bf16* y    = (__bf16*)alloc((size_t)MROWS * D_ * 2);        // ln out / attn out
  __bf16* qkvb = (__bf16*)alloc((size_t)MROWS * 3 * D_ * 2);
  __bf16* vtb  = (__bf16*)alloc((size_t)B_ * 1024 * 576 * 2);   // V^T per (b,h)
  __bf16* mid  = (__bf16*)alloc((size_t)MROWS * DFF_ * 2);
  __bf16* wsl  = (__bf16*)alloc((size_t)12582912 * 2);          // wq|wo|w1|w2 bf16
  int*    Te   = (int*)alloc((size_t)B_ * 576 * 4);
  int*    TeMn = (int*)alloc((size_t)B_ * 9 * 4);
  int*    TeMx = (int*)alloc((size_t)B_ * 9 * 4);
  int*    Cnt  = (int*)alloc((size_t)B_ * 256 * 4);
  (void)ws_size; (void)in_sizes; (void)n_in; (void)out_size;
  __bf16* wq  = wsl;
  __bf16* wo  = wsl + 3145728;
  __bf16* w1b = wsl + 4194304;
  __bf16* w2b = wsl + 8388608;

  te_k<<<B_, 576, 0, stream>>>(query_time, in_time_idx, Te, TeMn, TeMx, Cnt);
  pool_k<<<dim3(32, B_), 256, 0, stream>>>(latents, in_time_idx, Cnt, time_emb_w, h);
  qrows_k<<<dim3(NCTX + LQ_, B_), 256, 0, stream>>>(ctx_emb, query_emb_w, time_emb_w,
                                                    query_idx, query_time, h);
  for (int l = 0; l < DEPTH; ++l) {
    cvt4_k<<<12288, 256, 0, stream>>>(qkv_w + (size_t)l * 3145728, out_w + (size_t)l * 1048576,
                                      w1 + (size_t)l * 4194304, w2 + (size_t)l * 4194304, wsl);

    ln_k<<<MROWS / 4, 256, 0, stream>>>(h, ln1_s + l * D_, ln1_b + l * D_, y);
    gemm_k<4><<<24 * GY, 256, 0, stream>>>(
        y, wq, qkv_b + (size_t)l * 3 * D_, qkvb, nullptr, vtb, 3 * D_, D_, 24);
    attn_k<<<dim3(9, H_, B_), 256, 0, stream>>>(qkvb, vtb, Te, TeMn, TeMx, y);
    gemm_k<1><<<8 * GY, 256, 0, stream>>>(
        y, wo, out_b + (size_t)l * D_, nullptr, h, nullptr, D_, D_, 8);
    ln_k<<<MROWS / 4, 256, 0, stream>>>(h, ln2_s + l * D_, ln2_b + l * D_, y);
    gemm_k<2><<<32 * GY, 256, 0, stream>>>(
        y, w1b, b1 + (size_t)l * DFF_, mid, nullptr, nullptr, DFF_, D_, 32);
    gemm_k<1><<<8 * GY, 256, 0, stream>>>(
        mid, w2b, b2 + (size_t)l * D_, nullptr, h, nullptr, D_, DFF_, 8);
  }
  out_k<<<(B_ * 512 * 256) / 256, 256, 0, stream>>>(h, (float*)d_out);
}

// Round 12
// 2950.131 us; speedup vs baseline: 1.0094x; 1.0094x over previous
//
#include <hip/hip_runtime.h>

// ---------- constants ----------
#define B_    16
#define NCTX  8
#define BIN_  256
#define LQ_   256
#define L_    520          // NCTX + BIN + LQ
#define LSEQ  1024
#define D_    1024
#define H_    16
#define DH    64
#define DFF_  4096
#define DEPTH 6
#define MROWS (B_ * L_)    // 8320 = 65 * 128
#define GY    65           // M tiles of 128

using bf16x8 = __attribute__((ext_vector_type(8))) __bf16;
using bf16x4 = __attribute__((ext_vector_type(4))) __bf16;
using f32x4  = __attribute__((ext_vector_type(4))) float;

#define DEV __device__ __forceinline__

// element offset into a [rows][64] bf16 tile, XOR-swizzled 16B chunks
DEV int swz(int r, int c) { return (r << 6) + (((c ^ r) & 7) << 3); }

#define GLDS16(g, l)                                                         \
  __builtin_amdgcn_global_load_lds(                                          \
      (__attribute__((address_space(1))) void*)(g),                          \
      (__attribute__((address_space(3))) void*)(l), 16, 0, 0)

// ---------- prologue kernels ----------

// Te[b][pos]: time key per decoder position, per-64-tile K-min / Q-max for
// attention tile skipping, plus time-bin histogram counts for pooling.
__global__ void te_k(const int* __restrict__ qtime, const int* __restrict__ tIdx,
                     int* __restrict__ Te, int* __restrict__ TeMinK,
                     int* __restrict__ TeMaxQ, int* __restrict__ cnts) {
  int b = blockIdx.x, pos = threadIdx.x;  // 576 threads
  __shared__ int smin[9], smax[9], hc[256];
  if (pos < 9) { smin[pos] = 0x7fffffff; smax[pos] = (int)0x80000000; }
  if (pos < 256) hc[pos] = 0;
  __syncthreads();
  int v;
  if (pos < NCTX) v = (int)0x80000000;
  else if (pos < NCTX + BIN_) v = pos - NCTX;
  else if (pos < L_) v = qtime[b * LQ_ + (pos - NCTX - BIN_)];
  else v = 0x7fffffff;
  Te[b * 576 + pos] = v;
  int vq = (pos < L_) ? v : (int)0x80000000;
  atomicMin(&smin[pos >> 6], v);
  atomicMax(&smax[pos >> 6], vq);
  for (int i = pos; i < LSEQ; i += 576) atomicAdd(&hc[tIdx[b * LSEQ + i]], 1);
  __syncthreads();
  if (pos < 9) { TeMinK[b * 9 + pos] = smin[pos]; TeMaxQ[b * 9 + pos] = smax[pos]; }
  if (pos < 256) cnts[b * 256 + pos] = hc[pos];
}

// histogram-style mean-pool: block (colgroup cg of 32 cols, b). Each latent
// element is read exactly once; LDS fp32 atomic accumulate per (bin, col).
__global__ __launch_bounds__(256) void pool_k(const float* __restrict__ latents,
                                              const int* __restrict__ tIdx,
                                              const int* __restrict__ cnts,
                                              const float* __restrict__ temb,
                                              float* __restrict__ h) {
  const int cg = blockIdx.x, b = blockIdx.y, tid = threadIdx.x;
  __shared__ float acc[256][33];
  __shared__ int sIdx[LSEQ];
  float* af = &acc[0][0];
  for (int i = tid; i < 256 * 33; i += 256) af[i] = 0.f;
#pragma unroll
  for (int j = 0; j < 4; ++j) sIdx[tid + 256 * j] = tIdx[b * LSEQ + tid + 256 * j];
  __syncthreads();
  const int col = tid & 31, rp = tid >> 5;
  const float* Lb = latents + (size_t)b * LSEQ * D_ + cg * 32 + col;
  for (int r = rp; r < LSEQ; r += 8)
    atomicAdd(&acc[sIdx[r]][col], Lb[(size_t)r * D_]);
  __syncthreads();
  for (int s = rp; s < 256; s += 8) {
    int c = cnts[b * 256 + s];
    float inv = 1.f / (float)(c > 0 ? c : 1);
    h[((size_t)b * L_ + NCTX + s) * D_ + cg * 32 + col] =
        acc[s][col] * inv + temb[(size_t)s * D_ + cg * 32 + col];
  }
}

// ctx rows (0..7) + query rows (264..519)
__global__ void qrows_k(const float* __restrict__ ctx,
                        const float* __restrict__ qemb,
                        const float* __restrict__ temb,
                        const int* __restrict__ qidx,
                        const int* __restrict__ qtime, float* __restrict__ h) {
  int r = blockIdx.x, b = blockIdx.y, tid = threadIdx.x;
  if (r < NCTX) {
    float4 v = ((const float4*)(ctx + ((size_t)b * NCTX + r) * D_))[tid];
    ((float4*)(h + ((size_t)b * L_ + r) * D_))[tid] = v;
  } else {
    int q = r - NCTX;
    int qi = qidx[b * LQ_ + q];
    int qt = qtime[b * LQ_ + q];
    float4 e = ((const float4*)(qemb + (size_t)qi * D_))[tid];
    float4 t = ((const float4*)(temb + (size_t)qt * D_))[tid];
    float4 o; o.x = e.x + t.x; o.y = e.y + t.y; o.z = e.z + t.z; o.w = e.w + t.w;
    ((float4*)(h + ((size_t)b * L_ + NCTX + BIN_ + q) * D_))[tid] = o;
  }
}

// one launch per layer: convert all 4 weight slabs fp32 -> bf16
__global__ void cvt4_k(const float* __restrict__ s0, const float* __restrict__ s1,
                       const float* __restrict__ s2, const float* __restrict__ s3,
                       __bf16* __restrict__ dst) {
  int i = blockIdx.x * 256 + threadIdx.x;  // 3145728 total float4s
  const float* s; int off;
  if (i < 786432)       { s = s0; off = i; }
  else if (i < 1048576) { s = s1; off = i - 786432; }
  else if (i < 2097152) { s = s2; off = i - 1048576; }
  else                  { s = s3; off = i - 2097152; }
  float4 v = ((const float4*)s)[off];
  bf16x4 o;
  o[0] = (__bf16)v.x; o[1] = (__bf16)v.y; o[2] = (__bf16)v.z; o[3] = (__bf16)v.w;
  ((bf16x4*)dst)[i] = o;
}

// LayerNorm over D=1024: wave-per-row, no LDS, no __syncthreads.
__global__ __launch_bounds__(256) void ln_k(const float* __restrict__ h,
                                            const float* __restrict__ s,
                                            const float* __restrict__ bb,
                                            __bf16* __restrict__ y) {
  const int lane = threadIdx.x & 63, wave = threadIdx.x >> 6;
  const int row = blockIdx.x * 4 + wave;
  const float4* hr = (const float4*)(h + (size_t)row * D_);
  float4 v[4];
  float sum = 0.f, sq = 0.f;
#pragma unroll
  for (int j = 0; j < 4; ++j) {
    v[j] = hr[lane + 64 * j];
    sum += v[j].x + v[j].y + v[j].z + v[j].w;
    sq += v[j].x * v[j].x + v[j].y * v[j].y + v[j].z * v[j].z + v[j].w * v[j].w;
  }
#pragma unroll
  for (int m = 32; m; m >>= 1) { sum += __shfl_xor(sum, m); sq += __shfl_xor(sq, m); }
  float mean = sum * (1.f / D_);
  float var  = sq * (1.f / D_) - mean * mean;
  float rstd = rsqrtf(var + 1e-5f);
#pragma unroll
  for (int j = 0; j < 4; ++j) {
    float4 sv = ((const float4*)s)[lane + 64 * j];
    float4 bv = ((const float4*)bb)[lane + 64 * j];
    bf16x4 o;
    o[0] = (__bf16)((v[j].x - mean) * rstd * sv.x + bv.x);
    o[1] = (__bf16)((v[j].y - mean) * rstd * sv.y + bv.y);
    o[2] = (__bf16)((v[j].z - mean) * rstd * sv.z + bv.z);
    o[3] = (__bf16)((v[j].w - mean) * rstd * sv.w + bv.w);
    *(bf16x4*)(y + (size_t)row * D_ + (lane + 64 * j) * 4) = o;
  }
}

// ---------- GEMM: C[M,N] = A[M,K] * Bw[N,K]^T + bias (128x128 tile) ----------
// Proven core (r3 fingerprint: 126us, VGPR 84, 32KB LDS): single-buffer,
// 2 barriers/K-step; XCD-bijective chunk + 8-row supertile bands.
// EPI 0: store bf16; 1: outF += val (fp32 residual); 2: gelu -> bf16
template <int EPI>
__global__ __launch_bounds__(256) void gemm_k(const __bf16* __restrict__ A,
                                              const __bf16* __restrict__ Bw,
                                              const float* __restrict__ bias,
                                              __bf16* __restrict__ outB,
                                              float* __restrict__ outF,
                                              int N, int K, int gx) {
  __shared__ __bf16 sA[128 * 64];
  __shared__ __bf16 sB[128 * 64];
  const int tid = threadIdx.x;
  const int lane = tid & 63, wave = tid >> 6;
  const int lr = lane & 15, lq = lane >> 4;
  const int wr = wave >> 1, wc = wave & 1;

  // XCD-bijective remap (gridDim.x % 8 == 0 always) then 8-row bands
  const int nwg = gridDim.x;
  int hid = blockIdx.x;
  int lid = (hid & 7) * (nwg >> 3) + (hid >> 3);
  int per_band = gx << 3;
  int band = lid / per_band;
  int rem = lid - band * per_band;
  int rows = min(8, GY - (band << 3));
  int by = (band << 3) + rem % rows;
  int bx = rem / rows;
  const size_t bm = (size_t)by * 128;
  const size_t bn = (size_t)bx * 128;

  f32x4 acc[4][4] = {};

  int stage_r[4], stage_src[4];
#pragma unroll
  for (int j = 0; j < 4; ++j) {
    int q = (wave * 4 + j) * 64 + lane;
    int r = q >> 3, c = q & 7;
    stage_r[j] = r;
    stage_src[j] = ((c ^ r) & 7) << 3;  // pre-swizzled global chunk
  }
  const __bf16* Ab = A + bm * (size_t)K;
  const __bf16* Bb = Bw + bn * (size_t)K;
  const int nk = K >> 6;
  for (int kt = 0; kt < nk; ++kt) {
    const __bf16* Ak = Ab + kt * 64;
    const __bf16* Bk = Bb + kt * 64;
#pragma unroll
    for (int j = 0; j < 4; ++j) {
      int r = stage_r[j];
      GLDS16(Ak + (size_t)r * K + stage_src[j], sA + (wave * 4 + j) * 512);
      GLDS16(Bk + (size_t)r * K + stage_src[j], sB + (wave * 4 + j) * 512);
    }
    __syncthreads();
#pragma unroll
    for (int kk = 0; kk < 2; ++kk) {
      bf16x8 af[4], bfm[4];
#pragma unroll
      for (int im = 0; im < 4; ++im)
        af[im] = *(const bf16x8*)(sA + swz(wr * 64 + im * 16 + lr, kk * 4 + lq));
#pragma unroll
      for (int in = 0; in < 4; ++in)
        bfm[in] = *(const bf16x8*)(sB + swz(wc * 64 + in * 16 + lr, kk * 4 + lq));
#pragma unroll
      for (int im = 0; im < 4; ++im)
#pragma unroll
        for (int in = 0; in < 4; ++in)
          acc[im][in] = __builtin_amdgcn_mfma_f32_16x16x32_bf16(af[im], bfm[in], acc[im][in], 0, 0, 0);
    }
    __syncthreads();
  }
  const int r0 = (int)bm + wr * 64 + lq * 4;
  const int c0 = (int)bn + wc * 64 + lr;
#pragma unroll
  for (int in = 0; in < 4; ++in) {
    int cg = c0 + in * 16;
    float bl = bias[cg];
#pragma unroll
    for (int im = 0; im < 4; ++im) {
      f32x4 v = acc[im][in];
#pragma unroll
      for (int i = 0; i < 4; ++i) {
        int rg = r0 + im * 16 + i;
        float val = v[i] + bl;
        if (EPI == 0) {
          outB[(size_t)rg * N + cg] = (__bf16)val;
        } else if (EPI == 1) {
          outF[(size_t)rg * N + cg] += val;
        } else {
          float g = 0.5f * val * (1.0f + erff(val * 0.70710678118f));
          outB[(size_t)rg * N + cg] = (__bf16)g;
        }
      }
    }
  }
}

// ---------- attention ----------
// grid (qt=9, h=16, b=16), 256 threads (4 waves); each wave owns 16 q rows.
// Q in registers; K staged swizzled; V staged with per-8-row chunk XOR so
// the PV gather hits all 32 banks (was 4-way conflicted). Fully-masked
// (qt,kt) tile pairs skipped (time keys sorted).
__global__ __launch_bounds__(256) void attn_k(const __bf16* __restrict__ qkv,
                                              const int* __restrict__ Te,
                                              const int* __restrict__ TeMinK,
                                              const int* __restrict__ TeMaxQ,
                                              __bf16* __restrict__ o) {
  const int qt = blockIdx.x, hh = blockIdx.y, b = blockIdx.z;
  const int tid = threadIdx.x;
  const int lane = tid & 63, wave = tid >> 6;
  const int lr = lane & 15, lq = lane >> 4;
  __shared__ __bf16 sK[64 * 64], sV[64 * 64];
  __shared__ __bf16 sP[4][16 * 64];
  __shared__ int sTq[64], sTk[64];

  if (tid < 64) sTq[tid] = Te[b * 576 + qt * 64 + tid];
  const int maxQ = TeMaxQ[b * 9 + qt];

  const __bf16* base = qkv + (size_t)b * L_ * (3 * D_) + hh * DH;

  // Q fragments in registers: this wave's 16 rows, lane (lr,lq) holds
  // Q[qt*64+wave*16+lr][kk*32 + lq*8 .. +8) for kk=0,1.
  bf16x8 qf0 = {}, qf1 = {};
  {
    int qrow = qt * 64 + wave * 16 + lr;
    if (qrow < L_) {
      const __bf16* qp = base + (size_t)qrow * (3 * D_);
      qf0 = *(const bf16x8*)(qp + lq * 8);
      qf1 = *(const bf16x8*)(qp + 32 + lq * 8);
    }
  }

  float m_run[4], l_run[4];
#pragma unroll
  for (int i = 0; i < 4; ++i) { m_run[i] = -1e30f; l_run[i] = 0.f; }
  f32x4 oacc[4] = {};
  const float scale = 0.125f;

  for (int kt = 0; kt < 9; ++kt) {
    if (TeMinK[b * 9 + kt] > maxQ) continue;  // tile fully masked (uniform)
    __syncthreads();  // previous tile fully consumed
    if (tid < 64) sTk[tid] = Te[b * 576 + kt * 64 + tid];
#pragma unroll
    for (int j = 0; j < 2; ++j) {
      int q = tid + j * 256;
      int r = q >> 3, c = q & 7;
      int rg = kt * 64 + r;
      bf16x8 kv = {}, vv = {};
      if (rg < L_) {
        kv = *(const bf16x8*)(base + D_ + (size_t)rg * (3 * D_) + c * 8);
        vv = *(const bf16x8*)(base + 2 * D_ + (size_t)rg * (3 * D_) + c * 8);
      }
      *(bf16x8*)(sK + swz(r, c)) = kv;                             // swizzled
      *(bf16x8*)(sV + r * 64 + ((c ^ ((r >> 3) & 7)) << 3)) = vv;  // chunk-XOR
    }
    __syncthreads();

    // S = Q K^T (wave strip: rows wave*16..+16, cols 0..64)
    f32x4 sacc[4] = {};
    __builtin_amdgcn_s_setprio(1);
#pragma unroll
    for (int kk = 0; kk < 2; ++kk) {
      bf16x8 aq = (kk == 0) ? qf0 : qf1;
#pragma unroll
      for (int cn = 0; cn < 4; ++cn) {
        bf16x8 bk = *(const bf16x8*)(sK + swz(cn * 16 + lr, kk * 4 + lq));
        sacc[cn] = __builtin_amdgcn_mfma_f32_16x16x32_bf16(aq, bk, sacc[cn], 0, 0, 0);
      }
    }
    __builtin_amdgcn_s_setprio(0);
    // mask + online softmax (rows: lq*4+i, cols: cn*16+lr)
    float sval[4][4], mt[4];
#pragma unroll
    for (int i = 0; i < 4; ++i) mt[i] = -1e30f;
#pragma unroll
    for (int cn = 0; cn < 4; ++cn) {
      int tk = sTk[cn * 16 + lr];
#pragma unroll
      for (int i = 0; i < 4; ++i) {
        int tq = sTq[wave * 16 + lq * 4 + i];
        float sv = sacc[cn][i] * scale + ((tq < tk) ? -1e9f : 0.f);
        sval[cn][i] = sv;
        mt[i] = fmaxf(mt[i], sv);
      }
    }
#pragma unroll
    for (int i = 0; i < 4; ++i) {
#pragma unroll
      for (int m = 1; m < 16; m <<= 1) mt[i] = fmaxf(mt[i], __shfl_xor(mt[i], m));
    }
    float fsc[4], lt[4];
    __bf16* sPw = sP[wave];
#pragma unroll
    for (int i = 0; i < 4; ++i) {
      float mnew = fmaxf(m_run[i], mt[i]);
      fsc[i] = __expf(m_run[i] - mnew);
      m_run[i] = mnew;
      lt[i] = 0.f;
    }
#pragma unroll
    for (int cn = 0; cn < 4; ++cn) {
#pragma unroll
      for (int i = 0; i < 4; ++i) {
        float p = __expf(sval[cn][i] - m_run[i]);
        lt[i] += p;
        int rp = lq * 4 + i;
        int kvx = cn * 16 + lr;
        sPw[(rp << 6) + ((((kvx >> 3) ^ rp) & 7) << 3) + (kvx & 7)] = (__bf16)p;
      }
    }
#pragma unroll
    for (int i = 0; i < 4; ++i) {
#pragma unroll
      for (int m = 1; m < 16; m <<= 1) lt[i] += __shfl_xor(lt[i], m);
      l_run[i] = l_run[i] * fsc[i] + lt[i];
    }
#pragma unroll
    for (int dn = 0; dn < 4; ++dn)
#pragma unroll
      for (int i = 0; i < 4; ++i) oacc[dn][i] *= fsc[i];

    // PV: O += P[16,64] * V[64,64]; gather base uses matching chunk-XOR
    __builtin_amdgcn_s_setprio(1);
#pragma unroll
    for (int kk = 0; kk < 2; ++kk) {
      bf16x8 ap = *(const bf16x8*)(sPw + swz(lr, kk * 4 + lq));
#pragma unroll
      for (int dn = 0; dn < 4; ++dn) {
        const int xc = ((dn * 2 + (lr >> 3)) ^ (kk * 4 + lq)) & 7;
        const __bf16* vb = sV + (kk * 32 + lq * 8) * 64 + (xc << 3) + (lr & 7);
        bf16x8 bv;
#pragma unroll
        for (int i2 = 0; i2 < 8; ++i2) bv[i2] = vb[i2 * 64];
        oacc[dn] = __builtin_amdgcn_mfma_f32_16x16x32_bf16(ap, bv, oacc[dn], 0, 0, 0);
      }
    }
    __builtin_amdgcn_s_setprio(0);
  }
  // write O (normalize)
#pragma unroll
  for (int dn = 0; dn < 4; ++dn) {
#pragma unroll
    for (int i = 0; i < 4; ++i) {
      int rg = qt * 64 + wave * 16 + lq * 4 + i;
      if (rg < L_) {
        float val = oacc[dn][i] / l_run[i];
        o[((size_t)b * L_ + rg) * D_ + hh * DH + dn * 16 + lr] = (__bf16)val;
      }
    }
  }
}

// copy h[:, 8:, :] -> out (fp32)
__global__ void out_k(const float* __restrict__ h, float* __restrict__ out) {
  int idx = blockIdx.x * 256 + threadIdx.x;  // float4 units, 16*512*256
  int c4 = idx & 255;
  int r = (idx >> 8) & 511;
  int b = idx >> 17;
  ((float4*)out)[idx] = ((const float4*)h)[((size_t)b * L_ + NCTX + r) * 256 + c4];
}

// ---------- host ----------
extern "C" void kernel_launch(void* const* d_in, const int* in_sizes, int n_in,
                              void* d_out, int out_size, void* d_ws, size_t ws_size,
                              hipStream_t stream) {
  const float* latents      = (const float*)d_in[0];
  const int*   in_time_idx  = (const int*)d_in[1];
  const int*   query_idx    = (const int*)d_in[4];
  const int*   query_time   = (const int*)d_in[5];
  const float* ctx_emb      = (const float*)d_in[8];
  const float* query_emb_w  = (const float*)d_in[9];
  const float* time_emb_w   = (const float*)d_in[10];
  const float* qkv_w        = (const float*)d_in[11];
  const float* qkv_b        = (const float*)d_in[12];
  const float* out_w        = (const float*)d_in[13];
  const float* out_b        = (const float*)d_in[14];
  const float* ln1_s        = (const float*)d_in[15];
  const float* ln1_b        = (const float*)d_in[16];
  const float* ln2_s        = (const float*)d_in[17];
  const float* ln2_b        = (const float*)d_in[18];
  const float* w1           = (const float*)d_in[19];
  const float* b1           = (const float*)d_in[20];
  const float* w2           = (const float*)d_in[21];
  const float* b2           = (const float*)d_in[22];

  size_t off = 0;
  auto alloc = [&](size_t n) { char* p = (char*)d_ws + off; off += (n + 255) & ~(size_t)255; return (void*)p; };
  float*  h    = (float*)alloc((size_t)MROWS * D_ * 4);
  __bf16* y    = (__bf16*)alloc((size_t)MROWS * D_ * 2);        // ln out / attn out
  __bf16* qkvb = (__bf16*)alloc((size_t)MROWS * 3 * D_ * 2);
  __bf16* mid  = (__bf16*)alloc((size_t)MROWS * DFF_ * 2);
  __bf16* wsl  = (__bf16*)alloc((size_t)12582912 * 2);          // wq|wo|w1|w2 bf16
  int*    Te   = (int*)alloc((size_t)B_ * 576 * 4);
  int*    TeMn = (int*)alloc((size_t)B_ * 9 * 4);
  int*    TeMx = (int*)alloc((size_t)B_ * 9 * 4);
  int*    Cnt  = (int*)alloc((size_t)B_ * 256 * 4);
  (void)ws_size; (void)in_sizes; (void)n_in; (void)out_size;
  __bf16* wq  = wsl;
  __bf16* wo  = wsl + 3145728;
  __bf16* w1b = wsl + 4194304;
  __bf16* w2b = wsl + 8388608;

  te_k<<<B_, 576, 0, stream>>>(query_time, in_time_idx, Te, TeMn, TeMx, Cnt);
  pool_k<<<dim3(32, B_), 256, 0, stream>>>(latents, in_time_idx, Cnt, time_emb_w, h);
  qrows_k<<<dim3(NCTX + LQ_, B_), 256, 0, stream>>>(ctx_emb, query_emb_w, time_emb_w,
                                                    query_idx, query_time, h);
  for (int l = 0; l < DEPTH; ++l) {
    cvt4_k<<<12288, 256, 0, stream>>>(qkv_w + (size_t)l * 3145728, out_w + (size_t)l * 1048576,
                                      w1 + (size_t)l * 4194304, w2 + (size_t)l * 4194304, wsl);

    ln_k<<<MROWS / 4, 256, 0, stream>>>(h, ln1_s + l * D_, ln1_b + l * D_, y);
    gemm_k<0><<<24 * GY, 256, 0, stream>>>(
        y, wq, qkv_b + (size_t)l * 3 * D_, qkvb, nullptr, 3 * D_, D_, 24);
    attn_k<<<dim3(9, H_, B_), 256, 0, stream>>>(qkvb, Te, TeMn, TeMx, y);
    gemm_k<1><<<8 * GY, 256, 0, stream>>>(
        y, wo, out_b + (size_t)l * D_, nullptr, h, D_, D_, 8);
    ln_k<<<MROWS / 4, 256, 0, stream>>>(h, ln2_s + l * D_, ln2_b + l * D_, y);
    gemm_k<2><<<32 * GY, 256, 0, stream>>>(
        y, w1b, b1 + (size_t)l * DFF_, mid, nullptr, DFF_, D_, 32);
    gemm_k<1><<<8 * GY, 256, 0, stream>>>(
        mid, w2b, b2 + (size_t)l * D_, nullptr, h, D_, DFF_, 8);
  }
  out_k<<<(B_ * 512 * 256) / 256, 256, 0, stream>>>(h, (float*)d_out);
}

// Round 13
// 2901.194 us; speedup vs baseline: 1.0264x; 1.0169x over previous
//
#include <hip/hip_runtime.h>

// ---------- constants ----------
#define B_    16
#define NCTX  8
#define BIN_  256
#define LQ_   256
#define L_    520          // NCTX + BIN + LQ
#define LSEQ  1024
#define D_    1024
#define H_    16
#define DH    64
#define DFF_  4096
#define DEPTH 6
#define MROWS (B_ * L_)    // 8320 = 65 * 128
#define GY    65           // M tiles of 128

using bf16x8 = __attribute__((ext_vector_type(8))) __bf16;
using bf16x4 = __attribute__((ext_vector_type(4))) __bf16;
using f32x4  = __attribute__((ext_vector_type(4))) float;

#define DEV __device__ __forceinline__

// element offset into a [rows][64] bf16 tile, XOR-swizzled 16B chunks
DEV int swz(int r, int c) { return (r << 6) + (((c ^ r) & 7) << 3); }

#define GLDS16(g, l)                                                         \
  __builtin_amdgcn_global_load_lds(                                          \
      (__attribute__((address_space(1))) void*)(g),                          \
      (__attribute__((address_space(3))) void*)(l), 16, 0, 0)

// ---------- prologue kernels ----------

// Te[b][pos]: time key per decoder position, per-64-tile K-min / Q-max for
// attention tile skipping, plus time-bin histogram counts for pooling.
__global__ void te_k(const int* __restrict__ qtime, const int* __restrict__ tIdx,
                     int* __restrict__ Te, int* __restrict__ TeMinK,
                     int* __restrict__ TeMaxQ, int* __restrict__ cnts) {
  int b = blockIdx.x, pos = threadIdx.x;  // 576 threads
  __shared__ int smin[9], smax[9], hc[256];
  if (pos < 9) { smin[pos] = 0x7fffffff; smax[pos] = (int)0x80000000; }
  if (pos < 256) hc[pos] = 0;
  __syncthreads();
  int v;
  if (pos < NCTX) v = (int)0x80000000;
  else if (pos < NCTX + BIN_) v = pos - NCTX;
  else if (pos < L_) v = qtime[b * LQ_ + (pos - NCTX - BIN_)];
  else v = 0x7fffffff;
  Te[b * 576 + pos] = v;
  int vq = (pos < L_) ? v : (int)0x80000000;
  atomicMin(&smin[pos >> 6], v);
  atomicMax(&smax[pos >> 6], vq);
  for (int i = pos; i < LSEQ; i += 576) atomicAdd(&hc[tIdx[b * LSEQ + i]], 1);
  __syncthreads();
  if (pos < 9) { TeMinK[b * 9 + pos] = smin[pos]; TeMaxQ[b * 9 + pos] = smax[pos]; }
  if (pos < 256) cnts[b * 256 + pos] = hc[pos];
}

// histogram-style mean-pool: block (colgroup cg of 32 cols, b). Each latent
// element is read exactly once; LDS fp32 atomic accumulate per (bin, col).
__global__ __launch_bounds__(256) void pool_k(const float* __restrict__ latents,
                                              const int* __restrict__ tIdx,
                                              const int* __restrict__ cnts,
                                              const float* __restrict__ temb,
                                              float* __restrict__ h) {
  const int cg = blockIdx.x, b = blockIdx.y, tid = threadIdx.x;
  __shared__ float acc[256][33];
  __shared__ int sIdx[LSEQ];
  float* af = &acc[0][0];
  for (int i = tid; i < 256 * 33; i += 256) af[i] = 0.f;
#pragma unroll
  for (int j = 0; j < 4; ++j) sIdx[tid + 256 * j] = tIdx[b * LSEQ + tid + 256 * j];
  __syncthreads();
  const int col = tid & 31, rp = tid >> 5;
  const float* Lb = latents + (size_t)b * LSEQ * D_ + cg * 32 + col;
  for (int r = rp; r < LSEQ; r += 8)
    atomicAdd(&acc[sIdx[r]][col], Lb[(size_t)r * D_]);
  __syncthreads();
  for (int s = rp; s < 256; s += 8) {
    int c = cnts[b * 256 + s];
    float inv = 1.f / (float)(c > 0 ? c : 1);
    h[((size_t)b * L_ + NCTX + s) * D_ + cg * 32 + col] =
        acc[s][col] * inv + temb[(size_t)s * D_ + cg * 32 + col];
  }
}

// ctx rows (0..7) + query rows (264..519)
__global__ void qrows_k(const float* __restrict__ ctx,
                        const float* __restrict__ qemb,
                        const float* __restrict__ temb,
                        const int* __restrict__ qidx,
                        const int* __restrict__ qtime, float* __restrict__ h) {
  int r = blockIdx.x, b = blockIdx.y, tid = threadIdx.x;
  if (r < NCTX) {
    float4 v = ((const float4*)(ctx + ((size_t)b * NCTX + r) * D_))[tid];
    ((float4*)(h + ((size_t)b * L_ + r) * D_))[tid] = v;
  } else {
    int q = r - NCTX;
    int qi = qidx[b * LQ_ + q];
    int qt = qtime[b * LQ_ + q];
    float4 e = ((const float4*)(qemb + (size_t)qi * D_))[tid];
    float4 t = ((const float4*)(temb + (size_t)qt * D_))[tid];
    float4 o; o.x = e.x + t.x; o.y = e.y + t.y; o.z = e.z + t.z; o.w = e.w + t.w;
    ((float4*)(h + ((size_t)b * L_ + NCTX + BIN_ + q) * D_))[tid] = o;
  }
}

// one launch per layer: convert all 4 weight slabs fp32 -> bf16
__global__ void cvt4_k(const float* __restrict__ s0, const float* __restrict__ s1,
                       const float* __restrict__ s2, const float* __restrict__ s3,
                       __bf16* __restrict__ dst) {
  int i = blockIdx.x * 256 + threadIdx.x;  // 3145728 total float4s
  const float* s; int off;
  if (i < 786432)       { s = s0; off = i; }
  else if (i < 1048576) { s = s1; off = i - 786432; }
  else if (i < 2097152) { s = s2; off = i - 1048576; }
  else                  { s = s3; off = i - 2097152; }
  float4 v = ((const float4*)s)[off];
  bf16x4 o;
  o[0] = (__bf16)v.x; o[1] = (__bf16)v.y; o[2] = (__bf16)v.z; o[3] = (__bf16)v.w;
  ((bf16x4*)dst)[i] = o;
}

// LayerNorm over D=1024: wave-per-row, no LDS, no __syncthreads.
__global__ __launch_bounds__(256) void ln_k(const float* __restrict__ h,
                                            const float* __restrict__ s,
                                            const float* __restrict__ bb,
                                            __bf16* __restrict__ y) {
  const int lane = threadIdx.x & 63, wave = threadIdx.x >> 6;
  const int row = blockIdx.x * 4 + wave;
  const float4* hr = (const float4*)(h + (size_t)row * D_);
  float4 v[4];
  float sum = 0.f, sq = 0.f;
#pragma unroll
  for (int j = 0; j < 4; ++j) {
    v[j] = hr[lane + 64 * j];
    sum += v[j].x + v[j].y + v[j].z + v[j].w;
    sq += v[j].x * v[j].x + v[j].y * v[j].y + v[j].z * v[j].z + v[j].w * v[j].w;
  }
#pragma unroll
  for (int m = 32; m; m >>= 1) { sum += __shfl_xor(sum, m); sq += __shfl_xor(sq, m); }
  float mean = sum * (1.f / D_);
  float var  = sq * (1.f / D_) - mean * mean;
  float rstd = rsqrtf(var + 1e-5f);
#pragma unroll
  for (int j = 0; j < 4; ++j) {
    float4 sv = ((const float4*)s)[lane + 64 * j];
    float4 bv = ((const float4*)bb)[lane + 64 * j];
    bf16x4 o;
    o[0] = (__bf16)((v[j].x - mean) * rstd * sv.x + bv.x);
    o[1] = (__bf16)((v[j].y - mean) * rstd * sv.y + bv.y);
    o[2] = (__bf16)((v[j].z - mean) * rstd * sv.z + bv.z);
    o[3] = (__bf16)((v[j].w - mean) * rstd * sv.w + bv.w);
    *(bf16x4*)(y + (size_t)row * D_ + (lane + 64 * j) * 4) = o;
  }
}

// ---------- GEMM: C[M,N] = A[M,K] * Bw[N,K]^T + bias (128x128 tile) ----------
// Proven core (r3 fingerprint: 126us, VGPR 84, 32KB LDS): single-buffer,
// 2 barriers/K-step; XCD-bijective chunk + 8-row supertile bands.
// EPI 0: store bf16; 1: outF += val (fp32 residual); 2: gelu -> bf16
template <int EPI>
__global__ __launch_bounds__(256) void gemm_k(const __bf16* __restrict__ A,
                                              const __bf16* __restrict__ Bw,
                                              const float* __restrict__ bias,
                                              __bf16* __restrict__ outB,
                                              float* __restrict__ outF,
                                              int N, int K, int gx) {
  __shared__ __bf16 sA[128 * 64];
  __shared__ __bf16 sB[128 * 64];
  const int tid = threadIdx.x;
  const int lane = tid & 63, wave = tid >> 6;
  const int lr = lane & 15, lq = lane >> 4;
  const int wr = wave >> 1, wc = wave & 1;

  // XCD-bijective remap (gridDim.x % 8 == 0 always) then 8-row bands
  const int nwg = gridDim.x;
  int hid = blockIdx.x;
  int lid = (hid & 7) * (nwg >> 3) + (hid >> 3);
  int per_band = gx << 3;
  int band = lid / per_band;
  int rem = lid - band * per_band;
  int rows = min(8, GY - (band << 3));
  int by = (band << 3) + rem % rows;
  int bx = rem / rows;
  const size_t bm = (size_t)by * 128;
  const size_t bn = (size_t)bx * 128;

  f32x4 acc[4][4] = {};

  int stage_r[4], stage_src[4];
#pragma unroll
  for (int j = 0; j < 4; ++j) {
    int q = (wave * 4 + j) * 64 + lane;
    int r = q >> 3, c = q & 7;
    stage_r[j] = r;
    stage_src[j] = ((c ^ r) & 7) << 3;  // pre-swizzled global chunk
  }
  const __bf16* Ab = A + bm * (size_t)K;
  const __bf16* Bb = Bw + bn * (size_t)K;
  const int nk = K >> 6;
  for (int kt = 0; kt < nk; ++kt) {
    const __bf16* Ak = Ab + kt * 64;
    const __bf16* Bk = Bb + kt * 64;
#pragma unroll
    for (int j = 0; j < 4; ++j) {
      int r = stage_r[j];
      GLDS16(Ak + (size_t)r * K + stage_src[j], sA + (wave * 4 + j) * 512);
      GLDS16(Bk + (size_t)r * K + stage_src[j], sB + (wave * 4 + j) * 512);
    }
    __syncthreads();
#pragma unroll
    for (int kk = 0; kk < 2; ++kk) {
      bf16x8 af[4], bfm[4];
#pragma unroll
      for (int im = 0; im < 4; ++im)
        af[im] = *(const bf16x8*)(sA + swz(wr * 64 + im * 16 + lr, kk * 4 + lq));
#pragma unroll
      for (int in = 0; in < 4; ++in)
        bfm[in] = *(const bf16x8*)(sB + swz(wc * 64 + in * 16 + lr, kk * 4 + lq));
#pragma unroll
      for (int im = 0; im < 4; ++im)
#pragma unroll
        for (int in = 0; in < 4; ++in)
          acc[im][in] = __builtin_amdgcn_mfma_f32_16x16x32_bf16(af[im], bfm[in], acc[im][in], 0, 0, 0);
    }
    __syncthreads();
  }
  const int r0 = (int)bm + wr * 64 + lq * 4;
  const int c0 = (int)bn + wc * 64 + lr;
#pragma unroll
  for (int in = 0; in < 4; ++in) {
    int cg = c0 + in * 16;
    float bl = bias[cg];
#pragma unroll
    for (int im = 0; im < 4; ++im) {
      f32x4 v = acc[im][in];
#pragma unroll
      for (int i = 0; i < 4; ++i) {
        int rg = r0 + im * 16 + i;
        float val = v[i] + bl;
        if (EPI == 0) {
          outB[(size_t)rg * N + cg] = (__bf16)val;
        } else if (EPI == 1) {
          outF[(size_t)rg * N + cg] += val;
        } else {
          float g = 0.5f * val * (1.0f + erff(val * 0.70710678118f));
          outB[(size_t)rg * N + cg] = (__bf16)g;
        }
      }
    }
  }
}

// ---------- attention ----------
// grid (qt=9, h=16, b=16), 256 threads (4 waves); each wave owns 16 q rows.
// Q kept in registers (no sQ stage): LDS 24.8KB -> 6 blocks/CU.
// Fully-masked (qt,kt) tile pairs are skipped (time keys sorted).
__global__ __launch_bounds__(256) void attn_k(const __bf16* __restrict__ qkv,
                                              const int* __restrict__ Te,
                                              const int* __restrict__ TeMinK,
                                              const int* __restrict__ TeMaxQ,
                                              __bf16* __restrict__ o) {
  const int qt = blockIdx.x, hh = blockIdx.y, b = blockIdx.z;
  const int tid = threadIdx.x;
  const int lane = tid & 63, wave = tid >> 6;
  const int lr = lane & 15, lq = lane >> 4;
  __shared__ __bf16 sK[64 * 64], sV[64 * 64];
  __shared__ __bf16 sP[4][16 * 64];
  __shared__ int sTq[64], sTk[64];

  if (tid < 64) sTq[tid] = Te[b * 576 + qt * 64 + tid];
  const int maxQ = TeMaxQ[b * 9 + qt];

  const __bf16* base = qkv + (size_t)b * L_ * (3 * D_) + hh * DH;

  // Q fragments in registers: this wave's 16 rows, lane (lr,lq) holds
  // Q[qt*64+wave*16+lr][kk*32 + lq*8 .. +8) for kk=0,1.
  bf16x8 qf0 = {}, qf1 = {};
  {
    int qrow = qt * 64 + wave * 16 + lr;
    if (qrow < L_) {
      const __bf16* qp = base + (size_t)qrow * (3 * D_);
      qf0 = *(const bf16x8*)(qp + lq * 8);
      qf1 = *(const bf16x8*)(qp + 32 + lq * 8);
    }
  }

  float m_run[4], l_run[4];
#pragma unroll
  for (int i = 0; i < 4; ++i) { m_run[i] = -1e30f; l_run[i] = 0.f; }
  f32x4 oacc[4] = {};
  const float scale = 0.125f;

  for (int kt = 0; kt < 9; ++kt) {
    if (TeMinK[b * 9 + kt] > maxQ) continue;  // tile fully masked (uniform)
    __syncthreads();  // previous tile fully consumed
    if (tid < 64) sTk[tid] = Te[b * 576 + kt * 64 + tid];
#pragma unroll
    for (int j = 0; j < 2; ++j) {
      int q = tid + j * 256;
      int r = q >> 3, c = q & 7;
      int rg = kt * 64 + r;
      bf16x8 kv = {}, vv = {};
      if (rg < L_) {
        kv = *(const bf16x8*)(base + D_ + (size_t)rg * (3 * D_) + c * 8);
        vv = *(const bf16x8*)(base + 2 * D_ + (size_t)rg * (3 * D_) + c * 8);
      }
      *(bf16x8*)(sK + swz(r, c)) = kv;       // swizzled
      *(bf16x8*)(sV + r * 64 + c * 8) = vv;  // linear
    }
    __syncthreads();

    // S = Q K^T (wave strip: rows wave*16..+16, cols 0..64)
    f32x4 sacc[4] = {};
    __builtin_amdgcn_s_setprio(1);
#pragma unroll
    for (int kk = 0; kk < 2; ++kk) {
      bf16x8 aq = (kk == 0) ? qf0 : qf1;
#pragma unroll
      for (int cn = 0; cn < 4; ++cn) {
        bf16x8 bk = *(const bf16x8*)(sK + swz(cn * 16 + lr, kk * 4 + lq));
        sacc[cn] = __builtin_amdgcn_mfma_f32_16x16x32_bf16(aq, bk, sacc[cn], 0, 0, 0);
      }
    }
    __builtin_amdgcn_s_setprio(0);
    // mask + online softmax (rows: lq*4+i, cols: cn*16+lr)
    float sval[4][4], mt[4];
#pragma unroll
    for (int i = 0; i < 4; ++i) mt[i] = -1e30f;
#pragma unroll
    for (int cn = 0; cn < 4; ++cn) {
      int tk = sTk[cn * 16 + lr];
#pragma unroll
      for (int i = 0; i < 4; ++i) {
        int tq = sTq[wave * 16 + lq * 4 + i];
        float sv = sacc[cn][i] * scale + ((tq < tk) ? -1e9f : 0.f);
        sval[cn][i] = sv;
        mt[i] = fmaxf(mt[i], sv);
      }
    }
#pragma unroll
    for (int i = 0; i < 4; ++i) {
#pragma unroll
      for (int m = 1; m < 16; m <<= 1) mt[i] = fmaxf(mt[i], __shfl_xor(mt[i], m));
    }
    float fsc[4], lt[4];
    __bf16* sPw = sP[wave];
#pragma unroll
    for (int i = 0; i < 4; ++i) {
      float mnew = fmaxf(m_run[i], mt[i]);
      fsc[i] = __expf(m_run[i] - mnew);
      m_run[i] = mnew;
      lt[i] = 0.f;
    }
#pragma unroll
    for (int cn = 0; cn < 4; ++cn) {
#pragma unroll
      for (int i = 0; i < 4; ++i) {
        float p = __expf(sval[cn][i] - m_run[i]);
        lt[i] += p;
        int rp = lq * 4 + i;
        int kvx = cn * 16 + lr;
        sPw[(rp << 6) + ((((kvx >> 3) ^ rp) & 7) << 3) + (kvx & 7)] = (__bf16)p;
      }
    }
#pragma unroll
    for (int i = 0; i < 4; ++i) {
#pragma unroll
      for (int m = 1; m < 16; m <<= 1) lt[i] += __shfl_xor(lt[i], m);
      l_run[i] = l_run[i] * fsc[i] + lt[i];
    }
#pragma unroll
    for (int dn = 0; dn < 4; ++dn)
#pragma unroll
      for (int i = 0; i < 4; ++i) oacc[dn][i] *= fsc[i];

    // PV: O += P[16,64] * V[64,64]
    __builtin_amdgcn_s_setprio(1);
#pragma unroll
    for (int kk = 0; kk < 2; ++kk) {
      bf16x8 ap = *(const bf16x8*)(sPw + swz(lr, kk * 4 + lq));
#pragma unroll
      for (int dn = 0; dn < 4; ++dn) {
        bf16x8 bv;
#pragma unroll
        for (int i2 = 0; i2 < 8; ++i2)
          bv[i2] = sV[(kk * 32 + lq * 8 + i2) * 64 + dn * 16 + lr];
        oacc[dn] = __builtin_amdgcn_mfma_f32_16x16x32_bf16(ap, bv, oacc[dn], 0, 0, 0);
      }
    }
    __builtin_amdgcn_s_setprio(0);
  }
  // write O (normalize)
#pragma unroll
  for (int dn = 0; dn < 4; ++dn) {
#pragma unroll
    for (int i = 0; i < 4; ++i) {
      int rg = qt * 64 + wave * 16 + lq * 4 + i;
      if (rg < L_) {
        float val = oacc[dn][i] / l_run[i];
        o[((size_t)b * L_ + rg) * D_ + hh * DH + dn * 16 + lr] = (__bf16)val;
      }
    }
  }
}

// copy h[:, 8:, :] -> out (fp32)
__global__ void out_k(const float* __restrict__ h, float* __restrict__ out) {
  int idx = blockIdx.x * 256 + threadIdx.x;  // float4 units, 16*512*256
  int c4 = idx & 255;
  int r = (idx >> 8) & 511;
  int b = idx >> 17;
  ((float4*)out)[idx] = ((const float4*)h)[((size_t)b * L_ + NCTX + r) * 256 + c4];
}

// ---------- host ----------
extern "C" void kernel_launch(void* const* d_in, const int* in_sizes, int n_in,
                              void* d_out, int out_size, void* d_ws, size_t ws_size,
                              hipStream_t stream) {
  const float* latents      = (const float*)d_in[0];
  const int*   in_time_idx  = (const int*)d_in[1];
  const int*   query_idx    = (const int*)d_in[4];
  const int*   query_time   = (const int*)d_in[5];
  const float* ctx_emb      = (const float*)d_in[8];
  const float* query_emb_w  = (const float*)d_in[9];
  const float* time_emb_w   = (const float*)d_in[10];
  const float* qkv_w        = (const float*)d_in[11];
  const float* qkv_b        = (const float*)d_in[12];
  const float* out_w        = (const float*)d_in[13];
  const float* out_b        = (const float*)d_in[14];
  const float* ln1_s        = (const float*)d_in[15];
  const float* ln1_b        = (const float*)d_in[16];
  const float* ln2_s        = (const float*)d_in[17];
  const float* ln2_b        = (const float*)d_in[18];
  const float* w1           = (const float*)d_in[19];
  const float* b1           = (const float*)d_in[20];
  const float* w2           = (const float*)d_in[21];
  const float* b2           = (const float*)d_in[22];

  size_t off = 0;
  auto alloc = [&](size_t n) { char* p = (char*)d_ws + off; off += (n + 255) & ~(size_t)255; return (void*)p; };
  float*  h    = (float*)alloc((size_t)MROWS * D_ * 4);
  __bf16* y    = (__bf16*)alloc((size_t)MROWS * D_ * 2);        // ln out / attn out
  __bf16* qkvb = (__bf16*)alloc((size_t)MROWS * 3 * D_ * 2);
  __bf16* mid  = (__bf16*)alloc((size_t)MROWS * DFF_ * 2);
  __bf16* wsl  = (__bf16*)alloc((size_t)12582912 * 2);          // wq|wo|w1|w2 bf16
  int*    Te   = (int*)alloc((size_t)B_ * 576 * 4);
  int*    TeMn = (int*)alloc((size_t)B_ * 9 * 4);
  int*    TeMx = (int*)alloc((size_t)B_ * 9 * 4);
  int*    Cnt  = (int*)alloc((size_t)B_ * 256 * 4);
  (void)ws_size; (void)in_sizes; (void)n_in; (void)out_size;
  __bf16* wq  = wsl;
  __bf16* wo  = wsl + 3145728;
  __bf16* w1b = wsl + 4194304;
  __bf16* w2b = wsl + 8388608;

  te_k<<<B_, 576, 0, stream>>>(query_time, in_time_idx, Te, TeMn, TeMx, Cnt);
  pool_k<<<dim3(32, B_), 256, 0, stream>>>(latents, in_time_idx, Cnt, time_emb_w, h);
  qrows_k<<<dim3(NCTX + LQ_, B_), 256, 0, stream>>>(ctx_emb, query_emb_w, time_emb_w,
                                                    query_idx, query_time, h);
  for (int l = 0; l < DEPTH; ++l) {
    cvt4_k<<<12288, 256, 0, stream>>>(qkv_w + (size_t)l * 3145728, out_w + (size_t)l * 1048576,
                                      w1 + (size_t)l * 4194304, w2 + (size_t)l * 4194304, wsl);

    ln_k<<<MROWS / 4, 256, 0, stream>>>(h, ln1_s + l * D_, ln1_b + l * D_, y);
    gemm_k<0><<<24 * GY, 256, 0, stream>>>(
        y, wq, qkv_b + (size_t)l * 3 * D_, qkvb, nullptr, 3 * D_, D_, 24);
    attn_k<<<dim3(9, H_, B_), 256, 0, stream>>>(qkvb, Te, TeMn, TeMx, y);
    gemm_k<1><<<8 * GY, 256, 0, stream>>>(
        y, wo, out_b + (size_t)l * D_, nullptr, h, D_, D_, 8);
    ln_k<<<MROWS / 4, 256, 0, stream>>>(h, ln2_s + l * D_, ln2_b + l * D_, y);
    gemm_k<2><<<32 * GY, 256, 0, stream>>>(
        y, w1b, b1 + (size_t)l * DFF_, mid, nullptr, DFF_, D_, 32);
    gemm_k<1><<<8 * GY, 256, 0, stream>>>(
        mid, w2b, b2 + (size_t)l * D_, nullptr, h, D_, DFF_, 8);
  }
  out_k<<<(B_ * 512 * 256) / 256, 256, 0, stream>>>(h, (float*)d_out);
}